// Round 12
// baseline (42.144 us; speedup 1.0000x reference)
//
#include <hip/hip_runtime.h>
#include <hip/hip_bf16.h>

// Two-kernel structure: tiny precompute kernel builds tables in ws, main
// kernel is a per-element scalar function with matvecs on MFMA:
//   g[9] = (x*s0..x*s3, s0..s3)             (softmax key-weights, scalar)
//   z[32] = M[32x8]*g + bc                  (z-MFMA, bc via f32 C-init)
//   out  = K8 + 0.495*W2*|z| + 0.505*W2M*g  (leaky = 0.505z+0.495|z|)
// Fused-K trick (R9): B-fragment packs k-groups [g_hi | g_hi | g_lo | 0]; the
// matching A-fragment packs [M_hi | M_lo | M_hi | 0], so ONE 16x16x32 MFMA
// computes all three hi/lo cross terms. Per eg: 6 MFMAs.
// MFMA chaining: z output (lane g holds h = {4g..4g+3, 16+4g..16+4g+3}) IS a
// valid B-fragment for the out-MFMA with A3 precomputed in k-order
// H(g,j) = (j<4 ? 4g+j : 16+4g+(j-4)).
// bf16 error control: A operands hi/lo split (precomputed), g and |z| hi/lo
// split at runtime via v_cvt_pk_bf16_f32; biases exact via f32 C-init.
// Softmax: no max-subtract (|scores·log2e/4| bounded ~5, exp2 can't overflow).
// R11: plain stores (nt cost 2.2us -- L2 write-combining wins for streams).
// R12: pairwise chunk software-pipelining -- two chunks' softmax i-loops
// interleaved (2x ILP in the serial exp2 phase), then A's egs, then B's.
// Per-chunk math textually identical to R11.
//
// ws dword layout:
//   [0,16) sa  [16,32) sb  [32,48) sc      score quadratics (log2e folded)
//   48   A1[hb2][lane64][4]   (512)  fused z-MFMA A  [M_hi|M_lo|M_hi|0]
//   560  A2[lane64][4]        (256)  fused 0.505*W2M [hi|lo|hi|0]
//   816  A3[part2][lane64][4] (512)  0.495*W2 frags (H-permuted k, hi/lo)
//   1328 BC[lane64][8]  f32   (512)  z C-init  bc[16hb+4g+r]
//   1840 K8[lane64][4]  f32   (256)  out C-init 0.505*W2*bc + b2

#define WS_SA 0
#define WS_SB 16
#define WS_SC 32
#define WS_A1 48
#define WS_A2 560
#define WS_A3 816
#define WS_BC 1328
#define WS_K8 1840

using f32x4 = __attribute__((ext_vector_type(4))) float;
using bf16x8 = __attribute__((ext_vector_type(8))) short;

union FragU {
  unsigned u[4];
  bf16x8 v;
};

__device__ inline f32x4 mfma16(bf16x8 a, bf16x8 b, f32x4 c) {
  return __builtin_amdgcn_mfma_f32_16x16x32_bf16(a, b, c, 0, 0, 0);
}

__device__ inline unsigned short bf16_rne(float f) {
  unsigned u = __float_as_uint(f);
  unsigned lsb = (u >> 16) & 1u;
  u += 0x7fffu + lsb;
  return (unsigned short)(u >> 16);
}
__device__ inline float bf16_f32(unsigned short h) {
  return __uint_as_float(((unsigned)h) << 16);
}
__device__ inline unsigned pack2(unsigned short lo, unsigned short hi) {
  return (unsigned)lo | ((unsigned)hi << 16);
}
// hot-path pack: single v_cvt_pk_bf16_f32 (a -> low16, b -> high16), RNE
__device__ inline unsigned cvt2(float a, float b) {
  unsigned r;
  asm("v_cvt_pk_bf16_f32 %0, %1, %2" : "=v"(r) : "v"(a), "v"(b));
  return r;
}
// same, with |a|,|b| via free VOP3 input modifiers
__device__ inline unsigned cvt2abs(float a, float b) {
  unsigned r;
  asm("v_cvt_pk_bf16_f32 %0, abs(%1), abs(%2)" : "=v"(r) : "v"(a), "v"(b));
  return r;
}
__device__ inline float lo_f32(unsigned u) { return __uint_as_float(u << 16); }
__device__ inline float hi_f32(unsigned u) {
  return __uint_as_float(u & 0xffff0000u);
}
// pin a wave-uniform value into an SGPR
__device__ inline float uni(float v) {
  return __int_as_float(__builtin_amdgcn_readfirstlane(__float_as_int(v)));
}

__global__ __launch_bounds__(256) void precompute_kernel(
    const float* __restrict__ W0, const float* __restrict__ b0,
    const float* __restrict__ Wqkv, const float* __restrict__ bqkv,
    const float* __restrict__ Wo, const float* __restrict__ bo,
    const float* __restrict__ W1, const float* __restrict__ b1,
    const float* __restrict__ W2, const float* __restrict__ b2,
    float* __restrict__ wsf) {
  unsigned* wsu = (unsigned*)wsf;
  __shared__ float P[4][48], Q[4][48], Wc[32][16];
  __shared__ float M[32][8], bcs[32], W2M[16][8], c8[16];
  const int tid = threadIdx.x;

  // tokens -> qkv affine coefficients
  for (int idx = tid; idx < 4 * 48; idx += 256) {
    int t = idx / 48, f = idx % 48;
    float p = 0.f, q = 0.f;
    for (int e = 0; e < 16; ++e) {
      float w = Wqkv[f * 16 + e];
      p += W0[t * 16 + e] * w;
      q += b0[t * 16 + e] * w;
    }
    P[t][f] = p;
    Q[t][f] = q + bqkv[f];
  }
  // Wc = W1 * Wo (out_proj folded into post_fc1)
  for (int idx = tid; idx < 32 * 16; idx += 256) {
    int h = idx / 16, e = idx % 16;
    float acc = 0.f;
    for (int ep = 0; ep < 16; ++ep) acc += W1[h * 16 + ep] * Wo[ep * 16 + e];
    Wc[h][e] = acc;
  }
  __syncthreads();

  const float SCL = 0.25f * 1.4426950408889634f;  // 1/sqrt(16) * log2(e)
  for (int idx = tid; idx < 16; idx += 256) {
    int i = idx / 4, j = idx % 4;
    float a = 0.f, b = 0.f, c = 0.f;
    for (int e = 0; e < 16; ++e) {
      float pq = P[i][e], qq = Q[i][e];
      float pk = P[j][16 + e], qk = Q[j][16 + e];
      a += pq * pk;
      b += pq * qk + qq * pk;
      c += qq * qk;
    }
    wsf[WS_SA + idx] = a * SCL;
    wsf[WS_SB + idx] = b * SCL;
    wsf[WS_SC + idx] = c * SCL;
  }
  for (int idx = tid; idx < 32; idx += 256) {
    float acc = b1[idx];
    for (int ep = 0; ep < 16; ++ep) acc += W1[idx * 16 + ep] * bo[ep];
    bcs[idx] = acc;
  }
  // M[h][0..3] = U (coeff of x*s_j), M[h][4..7] = V (coeff of s_j), 1/4 folded
  for (int idx = tid; idx < 256; idx += 256) {
    int h = idx >> 3, k = idx & 7, j = k & 3;
    float acc = 0.f;
    if (k < 4)
      for (int e = 0; e < 16; ++e) acc += Wc[h][e] * P[j][32 + e];
    else
      for (int e = 0; e < 16; ++e) acc += Wc[h][e] * Q[j][32 + e];
    M[h][k] = 0.25f * acc;
  }
  __syncthreads();
  for (int idx = tid; idx < 128; idx += 256) {
    int o = idx >> 3, k = idx & 7;
    float acc = 0.f;
    for (int h = 0; h < 32; ++h) acc += W2[o * 32 + h] * M[h][k];
    W2M[o][k] = acc;
  }
  for (int idx = tid; idx < 16; idx += 256) {
    float acc = 0.f;
    for (int h = 0; h < 32; ++h) acc += W2[idx * 32 + h] * bcs[h];
    c8[idx] = acc;
  }
  __syncthreads();

  // build per-lane MFMA fragments (first wave only)
  if (tid < 64) {
    const int lane = tid;
    const int gg = lane >> 4, row = lane & 15;
    // A1 fused: k-groups [M_hi | M_lo | M_hi | 0] per hb half
    for (int hb = 0; hb < 2; ++hb) {
      int h = 16 * hb + row;
      for (int dw = 0; dw < 4; ++dw) {
        float m0 = M[h][2 * dw];
        float m1 = M[h][2 * dw + 1];
        unsigned short h0 = bf16_rne(m0), h1 = bf16_rne(m1);
        unsigned short l0 = bf16_rne(m0 - bf16_f32(h0));
        unsigned short l1 = bf16_rne(m1 - bf16_f32(h1));
        unsigned hi = pack2(h0, h1), lo = pack2(l0, l1);
        unsigned val = (gg == 1) ? lo : ((gg == 3) ? 0u : hi);
        wsu[WS_A1 + (hb * 64 + lane) * 4 + dw] = val;
      }
    }
    // A2 fused: 0.505*W2M, k-groups [hi | lo | hi | 0]
    for (int dw = 0; dw < 4; ++dw) {
      float m0 = 0.505f * W2M[row][2 * dw];
      float m1 = 0.505f * W2M[row][2 * dw + 1];
      unsigned short h0 = bf16_rne(m0), h1 = bf16_rne(m1);
      unsigned short l0 = bf16_rne(m0 - bf16_f32(h0));
      unsigned short l1 = bf16_rne(m1 - bf16_f32(h1));
      unsigned hi = pack2(h0, h1), lo = pack2(l0, l1);
      unsigned val = (gg == 1) ? lo : ((gg == 3) ? 0u : hi);
      wsu[WS_A2 + lane * 4 + dw] = val;
    }
    // A3: 0.495*W2 with H-permuted k so z-MFMA output is a valid B-frag
    for (int dw = 0; dw < 4; ++dw) {
      int j0 = 2 * dw, j1 = 2 * dw + 1;
      int H0 = (j0 < 4) ? 4 * gg + j0 : 16 + 4 * gg + (j0 - 4);
      int H1 = (j1 < 4) ? 4 * gg + j1 : 16 + 4 * gg + (j1 - 4);
      float m0 = 0.495f * W2[row * 32 + H0];
      float m1 = 0.495f * W2[row * 32 + H1];
      unsigned short h0 = bf16_rne(m0), h1 = bf16_rne(m1);
      unsigned short l0 = bf16_rne(m0 - bf16_f32(h0));
      unsigned short l1 = bf16_rne(m1 - bf16_f32(h1));
      wsu[WS_A3 + (0 * 64 + lane) * 4 + dw] = pack2(h0, h1);
      wsu[WS_A3 + (1 * 64 + lane) * 4 + dw] = pack2(l0, l1);
    }
    // C-init tables (exact f32 bias entry)
    for (int hb = 0; hb < 2; ++hb)
      for (int r = 0; r < 4; ++r)
        wsf[WS_BC + lane * 8 + hb * 4 + r] = bcs[16 * hb + 4 * gg + r];
    for (int r = 0; r < 4; ++r)
      wsf[WS_K8 + lane * 4 + r] = 0.505f * c8[4 * gg + r] + b2[4 * gg + r];
  }
}

__global__ __launch_bounds__(256) void subnet_mfma_kernel(
    const float* __restrict__ x, const float* __restrict__ wsf,
    float* __restrict__ out, int B) {
  const unsigned* wsu = (const unsigned*)wsf;
  const int lane = threadIdx.x & 63;
  const int wave = blockIdx.x * (blockDim.x >> 6) + (threadIdx.x >> 6);
  const int g = lane >> 4;

  // preload per-lane fragments (loop-invariant)
  FragU A1f0, A1f1, A2f, A3h, A3l;
#pragma unroll
  for (int dw = 0; dw < 4; ++dw) {
    A1f0.u[dw] = wsu[WS_A1 + (0 * 64 + lane) * 4 + dw];
    A1f1.u[dw] = wsu[WS_A1 + (1 * 64 + lane) * 4 + dw];
    A2f.u[dw] = wsu[WS_A2 + lane * 4 + dw];
    A3h.u[dw] = wsu[WS_A3 + (0 * 64 + lane) * 4 + dw];
    A3l.u[dw] = wsu[WS_A3 + (1 * 64 + lane) * 4 + dw];
  }
  f32x4 bc0, bc1, k8;
#pragma unroll
  for (int r = 0; r < 4; ++r) {
    bc0[r] = wsf[WS_BC + lane * 8 + r];
    bc1[r] = wsf[WS_BC + lane * 8 + 4 + r];
    k8[r] = wsf[WS_K8 + lane * 4 + r];
  }
  // score coefficients: sa/sc pinned to SGPR; sb in VGPR so each
  // v_fma reads at most one SGPR operand
  float sa[16], sb[16], sc[16];
#pragma unroll
  for (int i = 0; i < 16; ++i) {
    sa[i] = uni(wsf[WS_SA + i]);
    sb[i] = wsf[WS_SB + i];
    sc[i] = uni(wsf[WS_SC + i]);
  }
  const int permidx = (lane & 15) * 4;
  const bool useLo = (g >= 2);  // k-groups 2,3 take g_lo (group 3 = don't-care)
  const long nchunk = (long)(B >> 6);

  // prefetch the wave's 4 x values (independent loads in flight)
  const float* xp = x + (long)wave * 256 + lane;
  float xs4[4];
#pragma unroll
  for (int ci = 0; ci < 4; ++ci) {
    const long chunk = (long)wave * 4 + ci;
    xs4[ci] = (chunk < nchunk) ? __builtin_nontemporal_load(xp + ci * 64) : 0.f;
  }

  // store base: elem (wave*256 + lane&15), output component 4g
  float* op = out + ((long)wave * 256 + (lane & 15)) * 16 + 4 * g;

#pragma unroll 1
  for (int cp = 0; cp < 2; ++cp) {
    const long cA = (long)wave * 4 + 2 * cp;
    const long cB = cA + 1;
    const float xA = xs4[2 * cp];
    const float xB = xs4[2 * cp + 1];

    // ---- two softmaxes interleaved (2x ILP in the serial exp2 phase)
    float sA0 = 0.f, sA1 = 0.f, sA2 = 0.f, sA3 = 0.f;
    float sB0 = 0.f, sB1 = 0.f, sB2 = 0.f, sB3 = 0.f;
#pragma unroll
    for (int i = 0; i < 4; ++i) {
      float rA0 = (sa[i * 4 + 0] * xA + sb[i * 4 + 0]) * xA + sc[i * 4 + 0];
      float rA1 = (sa[i * 4 + 1] * xA + sb[i * 4 + 1]) * xA + sc[i * 4 + 1];
      float rA2 = (sa[i * 4 + 2] * xA + sb[i * 4 + 2]) * xA + sc[i * 4 + 2];
      float rA3 = (sa[i * 4 + 3] * xA + sb[i * 4 + 3]) * xA + sc[i * 4 + 3];
      float rB0 = (sa[i * 4 + 0] * xB + sb[i * 4 + 0]) * xB + sc[i * 4 + 0];
      float rB1 = (sa[i * 4 + 1] * xB + sb[i * 4 + 1]) * xB + sc[i * 4 + 1];
      float rB2 = (sa[i * 4 + 2] * xB + sb[i * 4 + 2]) * xB + sc[i * 4 + 2];
      float rB3 = (sa[i * 4 + 3] * xB + sb[i * 4 + 3]) * xB + sc[i * 4 + 3];
      float pA0 = __builtin_amdgcn_exp2f(rA0);
      float pA1 = __builtin_amdgcn_exp2f(rA1);
      float pA2 = __builtin_amdgcn_exp2f(rA2);
      float pA3 = __builtin_amdgcn_exp2f(rA3);
      float pB0 = __builtin_amdgcn_exp2f(rB0);
      float pB1 = __builtin_amdgcn_exp2f(rB1);
      float pB2 = __builtin_amdgcn_exp2f(rB2);
      float pB3 = __builtin_amdgcn_exp2f(rB3);
      float riA = __builtin_amdgcn_rcpf(pA0 + pA1 + pA2 + pA3);
      float riB = __builtin_amdgcn_rcpf(pB0 + pB1 + pB2 + pB3);
      sA0 += pA0 * riA;
      sA1 += pA1 * riA;
      sA2 += pA2 * riA;
      sA3 += pA3 * riA;
      sB0 += pB0 * riB;
      sB1 += pB1 * riB;
      sB2 += pB2 * riB;
      sB3 += pB3 * riB;
    }

    // ---- g vectors, hi/lo split bf16 pack (cvt_pk), both chunks
    float gvA[8] = {xA * sA0, xA * sA1, xA * sA2, xA * sA3, sA0, sA1, sA2, sA3};
    float gvB[8] = {xB * sB0, xB * sB1, xB * sB2, xB * sB3, sB0, sB1, sB2, sB3};
    unsigned ghA[4], glA[4], ghB[4], glB[4];
#pragma unroll
    for (int d = 0; d < 4; ++d) {
      unsigned phA = cvt2(gvA[2 * d], gvA[2 * d + 1]);
      ghA[d] = phA;
      glA[d] = cvt2(gvA[2 * d] - lo_f32(phA), gvA[2 * d + 1] - hi_f32(phA));
      unsigned phB = cvt2(gvB[2 * d], gvB[2 * d + 1]);
      ghB[d] = phB;
      glB[d] = cvt2(gvB[2 * d] - lo_f32(phB), gvB[2 * d + 1] - hi_f32(phB));
    }

    // ---- chunk A: 4 elem-groups
    if (cA < nchunk) {
      float* opA = op + (2 * cp) * 1024;
#pragma unroll
      for (int eg = 0; eg < 4; ++eg) {
        const int pidx = permidx + 64 * eg;
        FragU Bf;
#pragma unroll
        for (int d = 0; d < 4; ++d) {
          int bh = __builtin_amdgcn_ds_bpermute(pidx, (int)ghA[d]);
          int bl = __builtin_amdgcn_ds_bpermute(pidx, (int)glA[d]);
          Bf.u[d] = (unsigned)(useLo ? bl : bh);
        }
        f32x4 z0 = mfma16(A1f0.v, Bf.v, bc0);
        f32x4 z1 = mfma16(A1f1.v, Bf.v, bc1);
        float zz[8];
        zz[0] = z0[0]; zz[1] = z0[1]; zz[2] = z0[2]; zz[3] = z0[3];
        zz[4] = z1[0]; zz[5] = z1[1]; zz[6] = z1[2]; zz[7] = z1[3];
        FragU Zh, Zl;
#pragma unroll
        for (int d = 0; d < 4; ++d) {
          unsigned ph = cvt2abs(zz[2 * d], zz[2 * d + 1]);
          Zh.u[d] = ph;
          Zl.u[d] = cvt2(fabsf(zz[2 * d]) - lo_f32(ph),
                         fabsf(zz[2 * d + 1]) - hi_f32(ph));
        }
        f32x4 acc = mfma16(A2f.v, Bf.v, k8);
        acc = mfma16(A3h.v, Zh.v, acc);
        acc = mfma16(A3l.v, Zh.v, acc);
        acc = mfma16(A3h.v, Zl.v, acc);
        *reinterpret_cast<f32x4*>(opA + eg * 256) = acc;
      }
    }

    // ---- chunk B: 4 elem-groups
    if (cB < nchunk) {
      float* opB = op + (2 * cp + 1) * 1024;
#pragma unroll
      for (int eg = 0; eg < 4; ++eg) {
        const int pidx = permidx + 64 * eg;
        FragU Bf;
#pragma unroll
        for (int d = 0; d < 4; ++d) {
          int bh = __builtin_amdgcn_ds_bpermute(pidx, (int)ghB[d]);
          int bl = __builtin_amdgcn_ds_bpermute(pidx, (int)glB[d]);
          Bf.u[d] = (unsigned)(useLo ? bl : bh);
        }
        f32x4 z0 = mfma16(A1f0.v, Bf.v, bc0);
        f32x4 z1 = mfma16(A1f1.v, Bf.v, bc1);
        float zz[8];
        zz[0] = z0[0]; zz[1] = z0[1]; zz[2] = z0[2]; zz[3] = z0[3];
        zz[4] = z1[0]; zz[5] = z1[1]; zz[6] = z1[2]; zz[7] = z1[3];
        FragU Zh, Zl;
#pragma unroll
        for (int d = 0; d < 4; ++d) {
          unsigned ph = cvt2abs(zz[2 * d], zz[2 * d + 1]);
          Zh.u[d] = ph;
          Zl.u[d] = cvt2(fabsf(zz[2 * d]) - lo_f32(ph),
                         fabsf(zz[2 * d + 1]) - hi_f32(ph));
        }
        f32x4 acc = mfma16(A2f.v, Bf.v, k8);
        acc = mfma16(A3h.v, Zh.v, acc);
        acc = mfma16(A3l.v, Zh.v, acc);
        acc = mfma16(A3h.v, Zl.v, acc);
        *reinterpret_cast<f32x4*>(opB + eg * 256) = acc;
      }
    }
  }
}

extern "C" void kernel_launch(void* const* d_in, const int* in_sizes, int n_in,
                              void* d_out, int out_size, void* d_ws,
                              size_t ws_size, hipStream_t stream) {
  const float* x = (const float*)d_in[0];
  const float* W0 = (const float*)d_in[1];
  const float* b0 = (const float*)d_in[2];
  const float* Wqkv = (const float*)d_in[3];
  const float* bqkv = (const float*)d_in[4];
  const float* Wo = (const float*)d_in[5];
  const float* bo = (const float*)d_in[6];
  const float* W1 = (const float*)d_in[7];
  const float* b1 = (const float*)d_in[8];
  const float* W2 = (const float*)d_in[9];
  const float* b2 = (const float*)d_in[10];
  float* out = (float*)d_out;
  float* ws = (float*)d_ws;

  const int B = in_sizes[0];

  precompute_kernel<<<1, 256, 0, stream>>>(W0, b0, Wqkv, bqkv, Wo, bo, W1, b1,
                                           W2, b2, ws);

  // each wave: 4 chunks of 64 elems (processed in 2 pipelined pairs)
  const int blocks = (B + 1023) / 1024;
  subnet_mfma_kernel<<<blocks, 256, 0, stream>>>(x, ws, out, B);
}

// Round 13
// 36.717 us; speedup vs baseline: 1.1478x; 1.1478x over previous
//
#include <hip/hip_runtime.h>
#include <hip/hip_bf16.h>

// Two-kernel structure: tiny precompute kernel builds tables in ws, main
// kernel is a per-element scalar function with matvecs on MFMA:
//   g[9] = (x*s0..x*s3, s0..s3)             (softmax key-weights, scalar)
//   z[32] = M[32x8]*g + bc                  (z-MFMA, bc via f32 C-init)
//   out  = K8 + 0.495*W2*|z| + 0.505*W2M*g  (leaky = 0.505z+0.495|z|)
// Fused-K trick (R9): B-fragment packs k-groups [g_hi | g_hi | g_lo | 0]; the
// matching A-fragment packs [M_hi | M_lo | M_hi | 0], so ONE 16x16x32 MFMA
// computes all three hi/lo cross terms. Per eg: 6 MFMAs.
// MFMA chaining: z output (lane g holds h = {4g..4g+3, 16+4g..16+4g+3}) IS a
// valid B-fragment for the out-MFMA with A3 precomputed in k-order
// H(g,j) = (j<4 ? 4g+j : 16+4g+(j-4)).
// bf16 error control: A operands hi/lo split (precomputed), g and |z| hi/lo
// split at runtime via v_cvt_pk_bf16_f32; biases exact via f32 C-init.
// Softmax: no max-subtract (|scores·log2e/4| bounded ~5, exp2 can't overflow).
// R11: plain stores (nt cost 2.2us -- L2 write-combining wins for streams).
// R13: 8 chunks/wave (1024 blocks) -- amortizes the ~75-load wave preamble
// and launch overhead over 2x work; 8 x-loads in flight. Loop body is
// textually identical to R11 (R12's fat-body pipelining regressed).
//
// ws dword layout:
//   [0,16) sa  [16,32) sb  [32,48) sc      score quadratics (log2e folded)
//   48   A1[hb2][lane64][4]   (512)  fused z-MFMA A  [M_hi|M_lo|M_hi|0]
//   560  A2[lane64][4]        (256)  fused 0.505*W2M [hi|lo|hi|0]
//   816  A3[part2][lane64][4] (512)  0.495*W2 frags (H-permuted k, hi/lo)
//   1328 BC[lane64][8]  f32   (512)  z C-init  bc[16hb+4g+r]
//   1840 K8[lane64][4]  f32   (256)  out C-init 0.505*W2*bc + b2

#define WS_SA 0
#define WS_SB 16
#define WS_SC 32
#define WS_A1 48
#define WS_A2 560
#define WS_A3 816
#define WS_BC 1328
#define WS_K8 1840

#define CHUNKS_PER_WAVE 8

using f32x4 = __attribute__((ext_vector_type(4))) float;
using bf16x8 = __attribute__((ext_vector_type(8))) short;

union FragU {
  unsigned u[4];
  bf16x8 v;
};

__device__ inline f32x4 mfma16(bf16x8 a, bf16x8 b, f32x4 c) {
  return __builtin_amdgcn_mfma_f32_16x16x32_bf16(a, b, c, 0, 0, 0);
}

__device__ inline unsigned short bf16_rne(float f) {
  unsigned u = __float_as_uint(f);
  unsigned lsb = (u >> 16) & 1u;
  u += 0x7fffu + lsb;
  return (unsigned short)(u >> 16);
}
__device__ inline float bf16_f32(unsigned short h) {
  return __uint_as_float(((unsigned)h) << 16);
}
__device__ inline unsigned pack2(unsigned short lo, unsigned short hi) {
  return (unsigned)lo | ((unsigned)hi << 16);
}
// hot-path pack: single v_cvt_pk_bf16_f32 (a -> low16, b -> high16), RNE
__device__ inline unsigned cvt2(float a, float b) {
  unsigned r;
  asm("v_cvt_pk_bf16_f32 %0, %1, %2" : "=v"(r) : "v"(a), "v"(b));
  return r;
}
// same, with |a|,|b| via free VOP3 input modifiers
__device__ inline unsigned cvt2abs(float a, float b) {
  unsigned r;
  asm("v_cvt_pk_bf16_f32 %0, abs(%1), abs(%2)" : "=v"(r) : "v"(a), "v"(b));
  return r;
}
__device__ inline float lo_f32(unsigned u) { return __uint_as_float(u << 16); }
__device__ inline float hi_f32(unsigned u) {
  return __uint_as_float(u & 0xffff0000u);
}
// pin a wave-uniform value into an SGPR
__device__ inline float uni(float v) {
  return __int_as_float(__builtin_amdgcn_readfirstlane(__float_as_int(v)));
}

__global__ __launch_bounds__(256) void precompute_kernel(
    const float* __restrict__ W0, const float* __restrict__ b0,
    const float* __restrict__ Wqkv, const float* __restrict__ bqkv,
    const float* __restrict__ Wo, const float* __restrict__ bo,
    const float* __restrict__ W1, const float* __restrict__ b1,
    const float* __restrict__ W2, const float* __restrict__ b2,
    float* __restrict__ wsf) {
  unsigned* wsu = (unsigned*)wsf;
  __shared__ float P[4][48], Q[4][48], Wc[32][16];
  __shared__ float M[32][8], bcs[32], W2M[16][8], c8[16];
  const int tid = threadIdx.x;

  // tokens -> qkv affine coefficients
  for (int idx = tid; idx < 4 * 48; idx += 256) {
    int t = idx / 48, f = idx % 48;
    float p = 0.f, q = 0.f;
    for (int e = 0; e < 16; ++e) {
      float w = Wqkv[f * 16 + e];
      p += W0[t * 16 + e] * w;
      q += b0[t * 16 + e] * w;
    }
    P[t][f] = p;
    Q[t][f] = q + bqkv[f];
  }
  // Wc = W1 * Wo (out_proj folded into post_fc1)
  for (int idx = tid; idx < 32 * 16; idx += 256) {
    int h = idx / 16, e = idx % 16;
    float acc = 0.f;
    for (int ep = 0; ep < 16; ++ep) acc += W1[h * 16 + ep] * Wo[ep * 16 + e];
    Wc[h][e] = acc;
  }
  __syncthreads();

  const float SCL = 0.25f * 1.4426950408889634f;  // 1/sqrt(16) * log2(e)
  for (int idx = tid; idx < 16; idx += 256) {
    int i = idx / 4, j = idx % 4;
    float a = 0.f, b = 0.f, c = 0.f;
    for (int e = 0; e < 16; ++e) {
      float pq = P[i][e], qq = Q[i][e];
      float pk = P[j][16 + e], qk = Q[j][16 + e];
      a += pq * pk;
      b += pq * qk + qq * pk;
      c += qq * qk;
    }
    wsf[WS_SA + idx] = a * SCL;
    wsf[WS_SB + idx] = b * SCL;
    wsf[WS_SC + idx] = c * SCL;
  }
  for (int idx = tid; idx < 32; idx += 256) {
    float acc = b1[idx];
    for (int ep = 0; ep < 16; ++ep) acc += W1[idx * 16 + ep] * bo[ep];
    bcs[idx] = acc;
  }
  // M[h][0..3] = U (coeff of x*s_j), M[h][4..7] = V (coeff of s_j), 1/4 folded
  for (int idx = tid; idx < 256; idx += 256) {
    int h = idx >> 3, k = idx & 7, j = k & 3;
    float acc = 0.f;
    if (k < 4)
      for (int e = 0; e < 16; ++e) acc += Wc[h][e] * P[j][32 + e];
    else
      for (int e = 0; e < 16; ++e) acc += Wc[h][e] * Q[j][32 + e];
    M[h][k] = 0.25f * acc;
  }
  __syncthreads();
  for (int idx = tid; idx < 128; idx += 256) {
    int o = idx >> 3, k = idx & 7;
    float acc = 0.f;
    for (int h = 0; h < 32; ++h) acc += W2[o * 32 + h] * M[h][k];
    W2M[o][k] = acc;
  }
  for (int idx = tid; idx < 16; idx += 256) {
    float acc = 0.f;
    for (int h = 0; h < 32; ++h) acc += W2[idx * 32 + h] * bcs[h];
    c8[idx] = acc;
  }
  __syncthreads();

  // build per-lane MFMA fragments (first wave only)
  if (tid < 64) {
    const int lane = tid;
    const int gg = lane >> 4, row = lane & 15;
    // A1 fused: k-groups [M_hi | M_lo | M_hi | 0] per hb half
    for (int hb = 0; hb < 2; ++hb) {
      int h = 16 * hb + row;
      for (int dw = 0; dw < 4; ++dw) {
        float m0 = M[h][2 * dw];
        float m1 = M[h][2 * dw + 1];
        unsigned short h0 = bf16_rne(m0), h1 = bf16_rne(m1);
        unsigned short l0 = bf16_rne(m0 - bf16_f32(h0));
        unsigned short l1 = bf16_rne(m1 - bf16_f32(h1));
        unsigned hi = pack2(h0, h1), lo = pack2(l0, l1);
        unsigned val = (gg == 1) ? lo : ((gg == 3) ? 0u : hi);
        wsu[WS_A1 + (hb * 64 + lane) * 4 + dw] = val;
      }
    }
    // A2 fused: 0.505*W2M, k-groups [hi | lo | hi | 0]
    for (int dw = 0; dw < 4; ++dw) {
      float m0 = 0.505f * W2M[row][2 * dw];
      float m1 = 0.505f * W2M[row][2 * dw + 1];
      unsigned short h0 = bf16_rne(m0), h1 = bf16_rne(m1);
      unsigned short l0 = bf16_rne(m0 - bf16_f32(h0));
      unsigned short l1 = bf16_rne(m1 - bf16_f32(h1));
      unsigned hi = pack2(h0, h1), lo = pack2(l0, l1);
      unsigned val = (gg == 1) ? lo : ((gg == 3) ? 0u : hi);
      wsu[WS_A2 + lane * 4 + dw] = val;
    }
    // A3: 0.495*W2 with H-permuted k so z-MFMA output is a valid B-frag
    for (int dw = 0; dw < 4; ++dw) {
      int j0 = 2 * dw, j1 = 2 * dw + 1;
      int H0 = (j0 < 4) ? 4 * gg + j0 : 16 + 4 * gg + (j0 - 4);
      int H1 = (j1 < 4) ? 4 * gg + j1 : 16 + 4 * gg + (j1 - 4);
      float m0 = 0.495f * W2[row * 32 + H0];
      float m1 = 0.495f * W2[row * 32 + H1];
      unsigned short h0 = bf16_rne(m0), h1 = bf16_rne(m1);
      unsigned short l0 = bf16_rne(m0 - bf16_f32(h0));
      unsigned short l1 = bf16_rne(m1 - bf16_f32(h1));
      wsu[WS_A3 + (0 * 64 + lane) * 4 + dw] = pack2(h0, h1);
      wsu[WS_A3 + (1 * 64 + lane) * 4 + dw] = pack2(l0, l1);
    }
    // C-init tables (exact f32 bias entry)
    for (int hb = 0; hb < 2; ++hb)
      for (int r = 0; r < 4; ++r)
        wsf[WS_BC + lane * 8 + hb * 4 + r] = bcs[16 * hb + 4 * gg + r];
    for (int r = 0; r < 4; ++r)
      wsf[WS_K8 + lane * 4 + r] = 0.505f * c8[4 * gg + r] + b2[4 * gg + r];
  }
}

__global__ __launch_bounds__(256) void subnet_mfma_kernel(
    const float* __restrict__ x, const float* __restrict__ wsf,
    float* __restrict__ out, int B) {
  const unsigned* wsu = (const unsigned*)wsf;
  const int lane = threadIdx.x & 63;
  const int wave = blockIdx.x * (blockDim.x >> 6) + (threadIdx.x >> 6);
  const int g = lane >> 4;

  // preload per-lane fragments (loop-invariant)
  FragU A1f0, A1f1, A2f, A3h, A3l;
#pragma unroll
  for (int dw = 0; dw < 4; ++dw) {
    A1f0.u[dw] = wsu[WS_A1 + (0 * 64 + lane) * 4 + dw];
    A1f1.u[dw] = wsu[WS_A1 + (1 * 64 + lane) * 4 + dw];
    A2f.u[dw] = wsu[WS_A2 + lane * 4 + dw];
    A3h.u[dw] = wsu[WS_A3 + (0 * 64 + lane) * 4 + dw];
    A3l.u[dw] = wsu[WS_A3 + (1 * 64 + lane) * 4 + dw];
  }
  f32x4 bc0, bc1, k8;
#pragma unroll
  for (int r = 0; r < 4; ++r) {
    bc0[r] = wsf[WS_BC + lane * 8 + r];
    bc1[r] = wsf[WS_BC + lane * 8 + 4 + r];
    k8[r] = wsf[WS_K8 + lane * 4 + r];
  }
  // score coefficients: sa/sc pinned to SGPR; sb in VGPR so each
  // v_fma reads at most one SGPR operand
  float sa[16], sb[16], sc[16];
#pragma unroll
  for (int i = 0; i < 16; ++i) {
    sa[i] = uni(wsf[WS_SA + i]);
    sb[i] = wsf[WS_SB + i];
    sc[i] = uni(wsf[WS_SC + i]);
  }
  const int permidx = (lane & 15) * 4;
  const bool useLo = (g >= 2);  // k-groups 2,3 take g_lo (group 3 = don't-care)
  const long nchunk = (long)(B >> 6);

  // prefetch the wave's 8 x values (independent loads in flight)
  const float* xp = x + (long)wave * (64 * CHUNKS_PER_WAVE) + lane;
  float xs[CHUNKS_PER_WAVE];
#pragma unroll
  for (int ci = 0; ci < CHUNKS_PER_WAVE; ++ci) {
    const long chunk = (long)wave * CHUNKS_PER_WAVE + ci;
    xs[ci] = (chunk < nchunk) ? __builtin_nontemporal_load(xp + ci * 64) : 0.f;
  }

  // store base: elem (wave*512 + lane&15), output component 4g
  float* op =
      out + ((long)wave * (64 * CHUNKS_PER_WAVE) + (lane & 15)) * 16 + 4 * g;

#pragma unroll 1
  for (int ci = 0; ci < CHUNKS_PER_WAVE; ++ci) {
    const long chunk = (long)wave * CHUNKS_PER_WAVE + ci;
    if (chunk >= nchunk) break;
    const float xx = xs[ci];

    // ---- softmax over score quadratics -> key weights s0..s3
    // (no max-subtract: |r| bounded well under exp2 range)
    float s0 = 0.f, s1 = 0.f, s2 = 0.f, s3 = 0.f;
#pragma unroll
    for (int i = 0; i < 4; ++i) {
      float r0 = (sa[i * 4 + 0] * xx + sb[i * 4 + 0]) * xx + sc[i * 4 + 0];
      float r1 = (sa[i * 4 + 1] * xx + sb[i * 4 + 1]) * xx + sc[i * 4 + 1];
      float r2 = (sa[i * 4 + 2] * xx + sb[i * 4 + 2]) * xx + sc[i * 4 + 2];
      float r3 = (sa[i * 4 + 3] * xx + sb[i * 4 + 3]) * xx + sc[i * 4 + 3];
      float p0 = __builtin_amdgcn_exp2f(r0);
      float p1 = __builtin_amdgcn_exp2f(r1);
      float p2 = __builtin_amdgcn_exp2f(r2);
      float p3 = __builtin_amdgcn_exp2f(r3);
      float rinv = __builtin_amdgcn_rcpf(p0 + p1 + p2 + p3);
      s0 += p0 * rinv;
      s1 += p1 * rinv;
      s2 += p2 * rinv;
      s3 += p3 * rinv;
    }

    // ---- g vector, hi/lo split bf16 pack (cvt_pk)
    float gv[8] = {xx * s0, xx * s1, xx * s2, xx * s3, s0, s1, s2, s3};
    unsigned gh[4], gl[4];
#pragma unroll
    for (int d = 0; d < 4; ++d) {
      unsigned ph = cvt2(gv[2 * d], gv[2 * d + 1]);
      gh[d] = ph;
      gl[d] = cvt2(gv[2 * d] - lo_f32(ph), gv[2 * d + 1] - hi_f32(ph));
    }

#pragma unroll
    for (int eg = 0; eg < 4; ++eg) {
      const int pidx = permidx + 64 * eg;
      // fused B fragment: k-groups [g_hi | g_hi | g_lo | dc] of elem-group eg
      FragU Bf;
#pragma unroll
      for (int d = 0; d < 4; ++d) {
        int bh = __builtin_amdgcn_ds_bpermute(pidx, (int)gh[d]);
        int bl = __builtin_amdgcn_ds_bpermute(pidx, (int)gl[d]);
        Bf.u[d] = (unsigned)(useLo ? bl : bh);
      }
      // z = M*g + bc  (one MFMA per 16-h half: Mhi*ghi + Mlo*ghi + Mhi*glo)
      f32x4 z0 = mfma16(A1f0.v, Bf.v, bc0);
      f32x4 z1 = mfma16(A1f1.v, Bf.v, bc1);
      // |z| bf16 hi/lo pack (k-order matches A3's H-permutation)
      float zz[8];
      zz[0] = z0[0]; zz[1] = z0[1]; zz[2] = z0[2]; zz[3] = z0[3];
      zz[4] = z1[0]; zz[5] = z1[1]; zz[6] = z1[2]; zz[7] = z1[3];
      FragU Zh, Zl;
#pragma unroll
      for (int d = 0; d < 4; ++d) {
        unsigned ph = cvt2abs(zz[2 * d], zz[2 * d + 1]);
        Zh.u[d] = ph;
        Zl.u[d] = cvt2(fabsf(zz[2 * d]) - lo_f32(ph),
                       fabsf(zz[2 * d + 1]) - hi_f32(ph));
      }
      // out = K8 + 0.505*W2M*g (fused, 1 MFMA) + 0.495*W2*|z| (3 MFMA)
      f32x4 acc = mfma16(A2f.v, Bf.v, k8);
      acc = mfma16(A3h.v, Zh.v, acc);
      acc = mfma16(A3l.v, Zh.v, acc);
      acc = mfma16(A3h.v, Zl.v, acc);
      // store: 1KB contiguous per wave per eg (plain store through L2)
      *reinterpret_cast<f32x4*>(op + eg * 256) = acc;
    }
    op += 1024;  // next chunk: 64 elems * 16 floats
  }
}

extern "C" void kernel_launch(void* const* d_in, const int* in_sizes, int n_in,
                              void* d_out, int out_size, void* d_ws,
                              size_t ws_size, hipStream_t stream) {
  const float* x = (const float*)d_in[0];
  const float* W0 = (const float*)d_in[1];
  const float* b0 = (const float*)d_in[2];
  const float* Wqkv = (const float*)d_in[3];
  const float* bqkv = (const float*)d_in[4];
  const float* Wo = (const float*)d_in[5];
  const float* bo = (const float*)d_in[6];
  const float* W1 = (const float*)d_in[7];
  const float* b1 = (const float*)d_in[8];
  const float* W2 = (const float*)d_in[9];
  const float* b2 = (const float*)d_in[10];
  float* out = (float*)d_out;
  float* ws = (float*)d_ws;

  const int B = in_sizes[0];

  precompute_kernel<<<1, 256, 0, stream>>>(W0, b0, Wqkv, bqkv, Wo, bo, W1, b1,
                                           W2, b2, ws);

  // each wave: 8 chunks of 64 elems; 4 waves per block
  const int elemsPerBlock = 256 * 4 * CHUNKS_PER_WAVE / 4;  // 2048
  const int blocks = (B + elemsPerBlock - 1) / elemsPerBlock;
  subnet_mfma_kernel<<<blocks, 256, 0, stream>>>(x, ws, out, B);
}